// Round 5
// baseline (1316.979 us; speedup 1.0000x reference)
//
#include <hip/hip_runtime.h>
#include <hip/hip_bf16.h>

#define Nn 50000
#define Ee 1600000
#define Ff 64
#define Rr 5
#define Bb 4
#define Ll 4
#define Kk 2048
#define Mseg (Rr*Nn)

__global__ __launch_bounds__(256) void k_inv_init(int* __restrict__ inv){
  int i = blockIdx.x*256+threadIdx.x;
  if (i < Nn) inv[i] = -1;
}

__global__ __launch_bounds__(256) void k_inv_set(const int* __restrict__ tidx, int* __restrict__ inv){
  int k = blockIdx.x*256+threadIdx.x;
  if (k < Kk) inv[tidx[k]] = k;
}

// per-dst degree (CSR) + per-(rel,dst) counts (mean weights)
__global__ __launch_bounds__(256) void k_cnt(const int* __restrict__ ei, const int* __restrict__ et,
                                             int* __restrict__ cntd, int* __restrict__ cnt2){
  int e = blockIdx.x*256+threadIdx.x;
  if (e < Ee){
    int dst = ei[Ee + e];
    int r = et[e];
    atomicAdd(&cntd[dst], 1);
    atomicAdd(&cnt2[r*Nn + dst], 1);
  }
}

__global__ __launch_bounds__(256) void k_scan_blk(const int* __restrict__ cnt, int* __restrict__ part,
                                                  int* __restrict__ bsum, int n){
  __shared__ int s[256];
  int t = threadIdx.x; int idx = blockIdx.x*256+t;
  int v = (idx < n) ? cnt[idx] : 0;
  s[t] = v; __syncthreads();
  #pragma unroll
  for (int off=1; off<256; off<<=1){
    int x = (t>=off) ? s[t-off] : 0;
    __syncthreads();
    s[t] += x;
    __syncthreads();
  }
  if (idx < n) part[idx] = s[t] - v;
  if (t == 255) bsum[blockIdx.x] = s[255];
}

__global__ __launch_bounds__(1024) void k_scan_top(int* __restrict__ bsum, int nb){
  __shared__ int s[1024];
  int t = threadIdx.x;
  int v = (t < nb) ? bsum[t] : 0;
  s[t] = v; __syncthreads();
  #pragma unroll
  for (int off=1; off<1024; off<<=1){
    int x = (t>=off) ? s[t-off] : 0;
    __syncthreads();
    s[t] += x;
    __syncthreads();
  }
  if (t < nb) bsum[t] = s[t] - v;
}

__global__ __launch_bounds__(256) void k_scan_add(const int* __restrict__ part, const int* __restrict__ bsum,
                                                  int* __restrict__ rowptr, int n, int total){
  int idx = blockIdx.x*256+threadIdx.x;
  if (idx < n) rowptr[idx] = part[idx] + bsum[idx>>8];
  if (idx == 0) rowptr[n] = total;
}

// dst-major CSR; entry = src | rel<<16
__global__ __launch_bounds__(256) void k_place(const int* __restrict__ ei, const int* __restrict__ et,
                                               const int* __restrict__ rowptr, int* __restrict__ fill,
                                               unsigned* __restrict__ edges){
  int e = blockIdx.x*256+threadIdx.x;
  if (e < Ee){
    int src = ei[e];
    int dst = ei[Ee + e];
    int r = et[e];
    int pos = rowptr[dst] + atomicAdd(&fill[dst], 1);
    edges[pos] = (unsigned)src | ((unsigned)r << 16);
  }
}

// invc[dst*5+r] = 1/max(cnt2[r*Nn+dst],1)
__global__ __launch_bounds__(256) void k_invc(const int* __restrict__ cnt2, float* __restrict__ invc){
  int idx = blockIdx.x*256+threadIdx.x;
  if (idx < Mseg){
    int r = idx / Nn;
    int dst = idx - r*Nn;
    int c = cnt2[idx];
    invc[dst*Rr + r] = 1.0f / (float)((c > 1) ? c : 1);
  }
}

// Wall: 384x64 fp32. rows 0..319 = W_r, rows 320..383 = root.
__global__ __launch_bounds__(256) void k_wall(const float* __restrict__ bases, const float* __restrict__ comps,
                                              const float* __restrict__ roots, float* __restrict__ Wall){
  int idx = blockIdx.x*256+threadIdx.x;
  if (idx >= 384*64) return;
  int o = idx & 63, row = idx >> 6;
  float s;
  if (row < 320){
    int r = row >> 6, i = row & 63;
    s = 0.f;
    #pragma unroll
    for (int b=0;b<Bb;b++)
      s += comps[r*Bb+b] * bases[(b*Ff + i)*Ff + o];
  } else {
    int i = row - 320;
    s = roots[i*Ff + o];
  }
  Wall[idx] = s;
}

#define SVP 68

// H[c][n][o] = h[n][:] @ W_c   (c<5 rel transforms, c=5 root term). No activation.
// block = 64 nodes x 64 outs for one c; 4x4 register-blocked.
__global__ __launch_bounds__(256) void k_gemm(const float* __restrict__ h, const float* __restrict__ Wall,
                                              float* __restrict__ H)
{
  __shared__ __align__(16) float sW[64*64];
  __shared__ __align__(16) float sV[64*SVP];
  int t = threadIdx.x;
  int c = blockIdx.y;
  int n0 = blockIdx.x*64;
  int nlim = Nn - n0; if (nlim > 64) nlim = 64;
  int oq = (t & 15)*4, nq = (t >> 4)*4;
  float4 acc[4];
  #pragma unroll
  for (int j=0;j<4;j++) acc[j] = make_float4(0.f,0.f,0.f,0.f);

  #pragma unroll
  for (int idx=t; idx<1024; idx+=256){
    *(float4*)&sW[idx*4] = *(const float4*)&Wall[c*4096 + idx*4];
    int nl = idx>>4, iq = (idx&15)*4;
    float4 v = make_float4(0.f,0.f,0.f,0.f);
    if (nl < nlim) v = *(const float4*)&h[(size_t)(n0 + nl)*64 + iq];
    *(float4*)&sV[nl*SVP + iq] = v;
  }
  __syncthreads();
  #pragma unroll
  for (int i=0;i<64;i+=4){
    float4 v0 = *(const float4*)&sV[(nq+0)*SVP + i];
    float4 v1 = *(const float4*)&sV[(nq+1)*SVP + i];
    float4 v2 = *(const float4*)&sV[(nq+2)*SVP + i];
    float4 v3 = *(const float4*)&sV[(nq+3)*SVP + i];
    float4 w0 = *(const float4*)&sW[(i+0)*64 + oq];
    float4 w1 = *(const float4*)&sW[(i+1)*64 + oq];
    float4 w2 = *(const float4*)&sW[(i+2)*64 + oq];
    float4 w3 = *(const float4*)&sW[(i+3)*64 + oq];
    #define FMA4(A, V) \
      A.x += V.x*w0.x + V.y*w1.x + V.z*w2.x + V.w*w3.x; \
      A.y += V.x*w0.y + V.y*w1.y + V.z*w2.y + V.w*w3.y; \
      A.z += V.x*w0.z + V.y*w1.z + V.z*w2.z + V.w*w3.z; \
      A.w += V.x*w0.w + V.y*w1.w + V.z*w2.w + V.w*w3.w;
    FMA4(acc[0], v0)
    FMA4(acc[1], v1)
    FMA4(acc[2], v2)
    FMA4(acc[3], v3)
    #undef FMA4
  }

  #pragma unroll
  for (int j=0;j<4;j++){
    int n = n0 + nq + j;
    if (n < Nn) *(float4*)&H[((size_t)c*Nn + n)*64 + oq] = acc[j];
  }
}

// one wave per dst node: gather H[rel][src] rows, weight by invc, add root+bias, tanh.
__global__ __launch_bounds__(256) void k_agg(const unsigned* __restrict__ edges, const int* __restrict__ rowptr,
    const float* __restrict__ invc, const float* __restrict__ H, const float* __restrict__ bias,
    const int* __restrict__ inv, float* __restrict__ hn, float* __restrict__ sel, int layer)
{
  int dst = blockIdx.x*4 + (threadIdx.x >> 6);
  if (dst >= Nn) return;
  int f = threadIdx.x & 63;
  float w0 = invc[dst*Rr+0], w1 = invc[dst*Rr+1], w2 = invc[dst*Rr+2],
        w3 = invc[dst*Rr+3], w4 = invc[dst*Rr+4];
  int s = rowptr[dst], e = rowptr[dst+1];
  float acc = 0.f;
  int i = s;
  #define WSEL(r) ((r)==0 ? w0 : (r)==1 ? w1 : (r)==2 ? w2 : (r)==3 ? w3 : w4)
  for (; i+4 <= e; i+=4){
    unsigned u0 = edges[i+0], u1 = edges[i+1], u2 = edges[i+2], u3 = edges[i+3];
    float v0 = H[((size_t)(u0>>16)*Nn + (u0&0xffffu))*64 + f];
    float v1 = H[((size_t)(u1>>16)*Nn + (u1&0xffffu))*64 + f];
    float v2 = H[((size_t)(u2>>16)*Nn + (u2&0xffffu))*64 + f];
    float v3 = H[((size_t)(u3>>16)*Nn + (u3&0xffffu))*64 + f];
    acc += v0*WSEL(u0>>16) + v1*WSEL(u1>>16);
    acc += v2*WSEL(u2>>16) + v3*WSEL(u3>>16);
  }
  for (; i<e; i++){
    unsigned u = edges[i];
    acc += H[((size_t)(u>>16)*Nn + (u&0xffffu))*64 + f] * WSEL(u>>16);
  }
  #undef WSEL
  float root = H[((size_t)Rr*Nn + dst)*64 + f];
  float o = tanhf(acc + root + bias[f]);
  hn[(size_t)dst*64 + f] = o;
  int k = inv[dst];
  if (k >= 0) sel[(size_t)k*256 + layer*64 + f] = o;
}

__global__ __launch_bounds__(256) void k_w1eff(const float* __restrict__ w1, float* __restrict__ w1e){
  int idx = blockIdx.x*256+threadIdx.x;
  if (idx < 256*128){
    int i = idx >> 7, j = idx & 127;
    w1e[idx] = w1[i*128 + j] + w1[(i+256)*128 + j];
  }
}

__global__ __launch_bounds__(128) void k_mlp(const float* __restrict__ sel, const float* __restrict__ w1e,
    const float* __restrict__ b1, const float* __restrict__ w2, const float* __restrict__ b2,
    float* __restrict__ out)
{
  __shared__ float sfeat[256];
  __shared__ float partial[2];
  int k = blockIdx.x, j = threadIdx.x;
  for (int idx=j; idx<256; idx+=128) sfeat[idx] = sel[(size_t)k*256 + idx];
  __syncthreads();
  float a = b1[j];
  for (int i=0;i<256;i++) a += sfeat[i] * w1e[i*128 + j];
  a = fmaxf(a, 0.f);
  float v = a * w2[j];
  #pragma unroll
  for (int off=32; off>0; off>>=1) v += __shfl_down(v, off, 64);
  if ((j & 63) == 0) partial[j>>6] = v;
  __syncthreads();
  if (j == 0) out[k] = partial[0] + partial[1] + b2[0];
}

extern "C" void kernel_launch(void* const* d_in, const int* in_sizes, int n_in,
                              void* d_out, int out_size, void* d_ws, size_t ws_size,
                              hipStream_t stream){
  const float* x     = (const float*)d_in[0];
  const int*  ei     = (const int*)d_in[1];
  const int*  et     = (const int*)d_in[2];
  const int*  tidx   = (const int*)d_in[3];
  const float* bases = (const float*)d_in[4];
  const float* comps = (const float*)d_in[5];
  const float* roots = (const float*)d_in[6];
  const float* biases= (const float*)d_in[7];
  const float* w1    = (const float*)d_in[8];
  const float* b1    = (const float*)d_in[9];
  const float* w2    = (const float*)d_in[10];
  const float* b2    = (const float*)d_in[11];
  float* out = (float*)d_out;

  char* wsp = (char*)d_ws;
  size_t off = 0;
  auto alloc = [&](size_t bytes)->void*{ void* p = wsp + off; off += (bytes + 255) & ~size_t(255); return p; };
  float*    h0    = (float*)alloc(sizeof(float)*(size_t)Nn*Ff);        // 12.8 MB
  float*    H     = (float*)alloc(sizeof(float)*(size_t)6*Nn*Ff);      // 76.8 MB
  int*      cntd  = (int*)  alloc(sizeof(int)*(Nn));
  int*      cnt2  = (int*)  alloc(sizeof(int)*(Mseg));
  int*      part  = (int*)  alloc(sizeof(int)*(Nn));
  int*      bsum  = (int*)  alloc(sizeof(int)*1024);
  int*      rowptr= (int*)  alloc(sizeof(int)*(Nn+1));
  int*      fill  = (int*)  alloc(sizeof(int)*(Nn));
  unsigned* edges = (unsigned*)alloc(sizeof(unsigned)*(size_t)Ee);     // 6.4 MB
  float*    invc  = (float*)alloc(sizeof(float)*(size_t)Mseg);         // 1 MB
  float*    Wall  = (float*)alloc(sizeof(float)*384*64);
  float*    sel   = (float*)alloc(sizeof(float)*(size_t)Kk*256);       // 2 MB
  float*    w1e   = (float*)alloc(sizeof(float)*256*128);
  int*      inv   = (int*)  alloc(sizeof(int)*(size_t)Nn);
  (void)ws_size;

  const int NBd = (Nn + 255)/256;   // 196

  hipMemsetAsync(cntd, 0, sizeof(int)*Nn, stream);
  hipMemsetAsync(cnt2, 0, sizeof(int)*Mseg, stream);
  hipMemsetAsync(fill, 0, sizeof(int)*Nn, stream);
  k_inv_init<<<(Nn+255)/256, 256, 0, stream>>>(inv);
  k_inv_set<<<(Kk+255)/256, 256, 0, stream>>>(tidx, inv);
  k_w1eff<<<(256*128+255)/256, 256, 0, stream>>>(w1, w1e);
  k_cnt<<<(Ee+255)/256, 256, 0, stream>>>(ei, et, cntd, cnt2);
  k_scan_blk<<<NBd, 256, 0, stream>>>(cntd, part, bsum, Nn);
  k_scan_top<<<1, 1024, 0, stream>>>(bsum, NBd);
  k_scan_add<<<NBd, 256, 0, stream>>>(part, bsum, rowptr, Nn, Ee);
  k_place<<<(Ee+255)/256, 256, 0, stream>>>(ei, et, rowptr, fill, edges);
  k_invc<<<(Mseg+255)/256, 256, 0, stream>>>(cnt2, invc);

  const float* hc = x;
  for (int l=0;l<Ll;l++){
    k_wall<<<(384*64+255)/256, 256, 0, stream>>>(bases + (size_t)l*Bb*Ff*Ff, comps + (size_t)l*Rr*Bb,
                                                 roots + (size_t)l*Ff*Ff, Wall);
    dim3 g((Nn+63)/64, 6);
    k_gemm<<<g, 256, 0, stream>>>(hc, Wall, H);
    k_agg<<<(Nn+3)/4, 256, 0, stream>>>(edges, rowptr, invc, H, biases + (size_t)l*Ff, inv, h0, sel, l);
    hc = h0;
  }
  k_mlp<<<Kk, 128, 0, stream>>>(sel, w1e, b1, w2, b2, out);
}